// Round 15
// baseline (78.820 us; speedup 1.0000x reference)
//
#include <hip/hip_runtime.h>

typedef __attribute__((ext_vector_type(4))) float         f32x4;
typedef __attribute__((ext_vector_type(4), aligned(4))) float f32x4u;  // V odd -> rows only 4B-aligned
typedef __attribute__((ext_vector_type(8))) short         s16x8;
typedef __attribute__((ext_vector_type(2))) unsigned int  u32x2;

#define M_    2048      // B*S
#define H_    128       // K
#define V_    20001     // N
#define VP_   20096     // padded to 64
#define NT_   313       // n-tiles of 64
#define NTP_  320       // padded n-tiles: 8 XCD chunks of 40

// ws layout (bytes): row-major bf16 rows (256 B/row)
#define WS_XBF  0u            // 2048*256  = 524288
#define WS_EBF  524288u       // 20096*256 = 5144576
#define WS_XSQ  5668864u      // 2048*4
#define WS_ESQ  5677056u      // 20096*4
#define WS_BIA  5757440u      // 20096*4
#define WS_END  5837824u

__device__ __forceinline__ unsigned int f2bf(float f) {
    unsigned int u = __float_as_uint(f);
    u = (u + 0x7FFFu + ((u >> 16) & 1u)) >> 16;   // RNE
    return u;
}

// ---- prep: f32 -> bf16 rows + sums of squares + padded bias ----
__global__ __launch_bounds__(256)
void prep_kernel(const float* __restrict__ x, const float* __restrict__ emb,
                 const float* __restrict__ bias,
                 unsigned int* __restrict__ xbf, unsigned int* __restrict__ ebf,
                 float* __restrict__ xsq, float* __restrict__ esq,
                 float* __restrict__ biasp)
{
    const int g = blockIdx.x * 8 + (threadIdx.x >> 5);   // one row per 32-lane group
    const int l = threadIdx.x & 31;

    f32x4 v = { 0.f, 0.f, 0.f, 0.f };
    if (g < M_) {
        v = *(const f32x4*)(x + (size_t)g * H_ + l * 4);
    } else {
        int er = g - M_;
        if (er < V_) v = *(const f32x4*)(emb + (size_t)er * H_ + l * 4);
    }
    u32x2 p = { f2bf(v[0]) | (f2bf(v[1]) << 16),
                f2bf(v[2]) | (f2bf(v[3]) << 16) };
    if (g < M_) *(u32x2*)(xbf + (size_t)g * 64 + l * 2)        = p;
    else        *(u32x2*)(ebf + (size_t)(g - M_) * 64 + l * 2) = p;

    float ss = v[0]*v[0] + v[1]*v[1] + v[2]*v[2] + v[3]*v[3];
    ss += __shfl_xor(ss, 1);  ss += __shfl_xor(ss, 2);  ss += __shfl_xor(ss, 4);
    ss += __shfl_xor(ss, 8);  ss += __shfl_xor(ss, 16);
    if (l == 0) { if (g < M_) xsq[g] = ss; else esq[g - M_] = ss; }

    if (threadIdx.x < 8) {
        int idx = blockIdx.x * 8 + (int)threadIdx.x;
        if (idx < VP_) biasp[idx] = (idx < V_) ? bias[idx] : 0.f;
    }
}

// ---- GEMM 64x64, XCD-owned n-chunks (r14) + NON-TEMPORAL output stores ----
__global__ __launch_bounds__(256, 4)
void gemm_kernel(const unsigned int* __restrict__ xbf,
                 const unsigned int* __restrict__ ebf,
                 const float* __restrict__ xsq,
                 const float* __restrict__ esq,
                 const float* __restrict__ biasp,
                 float* __restrict__ out)
{
    // HW round-robins linear block id over 8 XCDs (grid is 1-D multiple of 8)
    const int bid = blockIdx.x;
    const int xcd = bid & 7;
    const int j   = bid >> 3;          // per-XCD sequential index, 0..1279
    const int dn  = j % 40;            // n-innermost within the XCD's chunk
    const int nt  = xcd * 40 + dn;
    if (nt >= NT_) return;             // padded tail (XCD 7), uniform exit
    const int mt  = ((j / 40) + 4 * xcd) & 31;   // stagger m-bands across XCDs
    const int m0  = mt * 64;
    const int n0  = nt * 64;

    __shared__ __align__(16) unsigned char smem[32 * 1024];
    unsigned char* a_t   = smem;               // 16 KB A tile (bf16, swizzled)
    unsigned char* b_t   = smem + 16 * 1024;   // 16 KB B tile
    unsigned char* otile = smem;               // aliased 16 KB f32 out tile

    const int tid  = threadIdx.x;
    const int lane = tid & 63;

    // stage A,B: swizzle via pre-swizzled SOURCE, linear LDS dest (validated r2)
    const char* asrc = (const char*)xbf + (size_t)m0 * 256;
    const char* bsrc = (const char*)ebf + (size_t)n0 * 256;   // n0+63 < VP, no guard
    #pragma unroll
    for (int i = 0; i < 4; ++i) {
        int c      = tid + i * 256;
        int row    = c >> 4;
        int within = (c & 15) * 16;
        int so     = row * 256 + (within ^ ((row & 7) << 4));
        unsigned ldsoff = (unsigned)(((tid & ~63) + i * 256) * 16);
        __builtin_amdgcn_global_load_lds(
            (const __attribute__((address_space(1))) unsigned int*)(asrc + so),
            (__attribute__((address_space(3))) unsigned int*)(a_t + ldsoff), 16, 0, 0);
        __builtin_amdgcn_global_load_lds(
            (const __attribute__((address_space(1))) unsigned int*)(bsrc + so),
            (__attribute__((address_space(3))) unsigned int*)(b_t + ldsoff), 16, 0, 0);
    }

    const int w  = tid >> 6;
    const int wm = w >> 1;
    const int wn = w & 1;
    const int lr = lane & 15;
    const int lk = lane >> 4;

    // hoisted epilogue operands (L2-hot ws; overlap with staging latency)
    const int   mloc0 = wm * 32 + lr;
    const int   mloc1 = mloc0 + 16;
    const float xs0   = xsq[m0 + mloc0];
    const float xs1   = xsq[m0 + mloc1];
    const int   nq0   = wn * 32 + lk * 4;
    const int   nq1   = nq0 + 16;
    const f32x4 es0   = *(const f32x4*)(esq   + n0 + nq0);
    const f32x4 es1   = *(const f32x4*)(esq   + n0 + nq1);
    const f32x4 bv0   = *(const f32x4*)(biasp + n0 + nq0);
    const f32x4 bv1   = *(const f32x4*)(biasp + n0 + nq1);

    __syncthreads();

    f32x4 acc[2][2] = {};
    #pragma unroll
    for (int kk = 0; kk < 4; ++kk) {
        int kb = kk * 64 + lk * 16;
        s16x8 a[2], b[2];
        #pragma unroll
        for (int mi = 0; mi < 2; ++mi) {
            int row = wm * 32 + mi * 16 + lr;
            a[mi] = *(const s16x8*)(&a_t[row * 256 + (kb ^ ((row & 7) << 4))]);
        }
        #pragma unroll
        for (int ni = 0; ni < 2; ++ni) {
            int row = wn * 32 + ni * 16 + lr;
            b[ni] = *(const s16x8*)(&b_t[row * 256 + (kb ^ ((row & 7) << 4))]);
        }
        #pragma unroll
        for (int mi = 0; mi < 2; ++mi)
            #pragma unroll
            for (int ni = 0; ni < 2; ++ni)
                // swapped operands: lane holds 4 consecutive n per fragment
                acc[mi][ni] = __builtin_amdgcn_mfma_f32_16x16x32_bf16(
                                  b[ni], a[mi], acc[mi][ni], 0, 0, 0);
    }

    __syncthreads();   // all waves done reading a_t/b_t -> safe to alias otile

    // write FINAL f32 values into swizzled otile
    // mapping: m = lane&15 (per mi), n = lk*4 + j (swapped m89 mapping)
    #pragma unroll
    for (int mi = 0; mi < 2; ++mi) {
        const int   mloc = (mi == 0) ? mloc0 : mloc1;
        const float xs   = (mi == 0) ? xs0   : xs1;
        #pragma unroll
        for (int ni = 0; ni < 2; ++ni) {
            const f32x4 es = (ni == 0) ? es0 : es1;
            const f32x4 bv = (ni == 0) ? bv0 : bv1;
            const int   nl = (ni == 0) ? nq0 : nq1;
            f32x4 r;
            #pragma unroll
            for (int jj = 0; jj < 4; ++jj) {
                float d2 = xs + es[jj] - 2.0f * acc[mi][ni][jj];
                r[jj] = bv[jj] - __builtin_amdgcn_sqrtf(fmaxf(d2, 0.0f));
            }
            *(f32x4*)(&otile[(mloc * 256 + nl * 4) ^ ((mloc & 7) << 4)]) = r;
        }
    }

    __syncthreads();

    // read back row-contiguous; NON-TEMPORAL stores keep the 164 MB write
    // stream out of L2 so input tiles stay resident.
    const int rb = w * 16;
    if (n0 + 63 < V_) {
        #pragma unroll
        for (int i = 0; i < 4; ++i) {
            int r = rb + i * 4 + lk;
            f32x4 v = *(const f32x4*)(&otile[(r * 256 + lr * 16) ^ ((r & 7) << 4)]);
            __builtin_nontemporal_store(v, (f32x4u*)(out + (size_t)(m0 + r) * V_ + n0 + lr * 4));
        }
    } else {
        #pragma unroll
        for (int i = 0; i < 4; ++i) {
            int r  = rb + i * 4 + lk;
            int gn = n0 + lr * 4;
            f32x4 v = *(const f32x4*)(&otile[(r * 256 + lr * 16) ^ ((r & 7) << 4)]);
            #pragma unroll
            for (int jj = 0; jj < 4; ++jj)
                if (gn + jj < V_)
                    __builtin_nontemporal_store(v[jj], out + (size_t)(m0 + r) * V_ + gn + jj);
        }
    }
}

// ---------------- fallback (round-1 single kernel) if ws too small ----------------
__global__ __launch_bounds__(256, 2)
void l2head_fallback(const float* __restrict__ x,
                     const float* __restrict__ emb,
                     const float* __restrict__ bias,
                     float* __restrict__ out)
{
    __shared__ unsigned char a_raw[64 * 256];
    __shared__ unsigned char b_raw[64 * 256];
    __shared__ float xsq[64];
    __shared__ float esq[64];
    __shared__ float bls[64];

    const int tid  = threadIdx.x;
    const int lane = tid & 63;
    const int m0   = blockIdx.x * 64;
    const int n0   = blockIdx.y * 64;

    if (tid < 64) {
        int gn = n0 + tid;
        bls[tid] = (gn < V_) ? bias[gn] : 0.0f;
    }
    {
        const f32x4* src = (const f32x4*)(x + (size_t)m0 * H_);
        #pragma unroll
        for (int i = 0; i < 8; ++i) {
            int f = tid + i * 256, row = f >> 5, c4 = f & 31;
            f32x4 v = src[f];
            u32x2 p = { f2bf(v[0]) | (f2bf(v[1]) << 16),
                        f2bf(v[2]) | (f2bf(v[3]) << 16) };
            int boff = (c4 * 8) ^ ((row & 7) << 4);
            *(u32x2*)(&a_raw[row * 256 + boff]) = p;
            float ss = v[0]*v[0] + v[1]*v[1] + v[2]*v[2] + v[3]*v[3];
            ss += __shfl_xor(ss, 1);  ss += __shfl_xor(ss, 2);
            ss += __shfl_xor(ss, 4);  ss += __shfl_xor(ss, 8);
            ss += __shfl_xor(ss, 16);
            if ((lane & 31) == 0) xsq[row] = ss;
        }
    }
    {
        #pragma unroll
        for (int i = 0; i < 8; ++i) {
            int f = tid + i * 256, row = f >> 5, c4 = f & 31;
            int gn = n0 + row;
            f32x4 v = { 0.f, 0.f, 0.f, 0.f };
            if (gn < V_) v = *(const f32x4*)(emb + (size_t)gn * H_ + c4 * 4);
            u32x2 p = { f2bf(v[0]) | (f2bf(v[1]) << 16),
                        f2bf(v[2]) | (f2bf(v[3]) << 16) };
            int boff = (c4 * 8) ^ ((row & 7) << 4);
            *(u32x2*)(&b_raw[row * 256 + boff]) = p;
            float ss = v[0]*v[0] + v[1]*v[1] + v[2]*v[2] + v[3]*v[3];
            ss += __shfl_xor(ss, 1);  ss += __shfl_xor(ss, 2);
            ss += __shfl_xor(ss, 4);  ss += __shfl_xor(ss, 8);
            ss += __shfl_xor(ss, 16);
            if ((lane & 31) == 0) esq[row] = ss;
        }
    }
    __syncthreads();

    const int w  = tid >> 6;
    const int wm = w >> 1;
    const int wn = w & 1;
    const int lr = lane & 15;
    const int lk = lane >> 4;

    f32x4 acc[2][2] = {};
    #pragma unroll
    for (int kk = 0; kk < 4; ++kk) {
        int kb = kk * 64 + lk * 16;
        s16x8 a[2], b[2];
        #pragma unroll
        for (int mi = 0; mi < 2; ++mi) {
            int row = wm * 32 + mi * 16 + lr;
            a[mi] = *(const s16x8*)(&a_raw[row * 256 + (kb ^ ((row & 7) << 4))]);
        }
        #pragma unroll
        for (int ni = 0; ni < 2; ++ni) {
            int row = wn * 32 + ni * 16 + lr;
            b[ni] = *(const s16x8*)(&b_raw[row * 256 + (kb ^ ((row & 7) << 4))]);
        }
        #pragma unroll
        for (int mi = 0; mi < 2; ++mi)
            #pragma unroll
            for (int ni = 0; ni < 2; ++ni)
                acc[mi][ni] = __builtin_amdgcn_mfma_f32_16x16x32_bf16(
                                  a[mi], b[ni], acc[mi][ni], 0, 0, 0);
    }

    #pragma unroll
    for (int mi = 0; mi < 2; ++mi) {
        int mbase = wm * 32 + mi * 16 + lk * 4;
        #pragma unroll
        for (int ni = 0; ni < 2; ++ni) {
            int nloc = wn * 32 + ni * 16 + lr;
            int gn   = n0 + nloc;
            if (gn < V_) {
                float es = esq[nloc];
                float bb = bls[nloc];
                #pragma unroll
                for (int j = 0; j < 4; ++j) {
                    int   mloc = mbase + j;
                    float d2   = xsq[mloc] + es - 2.0f * acc[mi][ni][j];
                    out[(size_t)(m0 + mloc) * V_ + gn] = bb - __builtin_sqrtf(fmaxf(d2, 0.0f));
                }
            }
        }
    }
}

extern "C" void kernel_launch(void* const* d_in, const int* in_sizes, int n_in,
                              void* d_out, int out_size, void* d_ws, size_t ws_size,
                              hipStream_t stream) {
    const float* x    = (const float*)d_in[0];
    const float* emb  = (const float*)d_in[1];
    const float* bias = (const float*)d_in[2];
    float* out        = (float*)d_out;

    if (ws_size >= WS_END) {
        unsigned char* ws = (unsigned char*)d_ws;
        unsigned int* xbf = (unsigned int*)(ws + WS_XBF);
        unsigned int* ebf = (unsigned int*)(ws + WS_EBF);
        float* xsq        = (float*)(ws + WS_XSQ);
        float* esq        = (float*)(ws + WS_ESQ);
        float* biasp      = (float*)(ws + WS_BIA);

        prep_kernel<<<(M_ + VP_) / 8, 256, 0, stream>>>(x, emb, bias, xbf, ebf, xsq, esq, biasp);
        gemm_kernel<<<dim3(NTP_ * 32), dim3(256), 0, stream>>>(xbf, ebf, xsq, esq, biasp, out);
    } else {
        dim3 grid(M_ / 64, (V_ + 63) / 64);
        l2head_fallback<<<grid, dim3(256), 0, stream>>>(x, emb, bias, out);
    }
}

// Round 16
// 43.627 us; speedup vs baseline: 1.8067x; 1.8067x over previous
//
#include <hip/hip_runtime.h>

typedef __attribute__((ext_vector_type(4))) float         f32x4;
typedef __attribute__((ext_vector_type(4), aligned(4))) float f32x4u;  // V odd -> rows only 4B-aligned
typedef __attribute__((ext_vector_type(8))) short         s16x8;
typedef __attribute__((ext_vector_type(2))) unsigned int  u32x2;

#define M_    2048      // B*S
#define H_    128       // K
#define V_    20001     // N
#define VP_   20096     // padded to 64
#define NT_   313       // n-tiles of 64
#define NTP_  320       // padded n-tiles: 8 XCD chunks of 40

// ws layout (bytes): row-major bf16 rows (256 B/row)
#define WS_XBF  0u            // 2048*256  = 524288
#define WS_EBF  524288u       // 20096*256 = 5144576
#define WS_XSQ  5668864u      // 2048*4
#define WS_ESQ  5677056u      // 20096*4
#define WS_BIA  5757440u      // 20096*4
#define WS_END  5837824u

__device__ __forceinline__ unsigned int f2bf(float f) {
    unsigned int u = __float_as_uint(f);
    u = (u + 0x7FFFu + ((u >> 16) & 1u)) >> 16;   // RNE
    return u;
}

// ---- prep: f32 -> bf16 rows + sums of squares + padded bias ----
__global__ __launch_bounds__(256)
void prep_kernel(const float* __restrict__ x, const float* __restrict__ emb,
                 const float* __restrict__ bias,
                 unsigned int* __restrict__ xbf, unsigned int* __restrict__ ebf,
                 float* __restrict__ xsq, float* __restrict__ esq,
                 float* __restrict__ biasp)
{
    const int g = blockIdx.x * 8 + (threadIdx.x >> 5);   // one row per 32-lane group
    const int l = threadIdx.x & 31;

    f32x4 v = { 0.f, 0.f, 0.f, 0.f };
    if (g < M_) {
        v = *(const f32x4*)(x + (size_t)g * H_ + l * 4);
    } else {
        int er = g - M_;
        if (er < V_) v = *(const f32x4*)(emb + (size_t)er * H_ + l * 4);
    }
    u32x2 p = { f2bf(v[0]) | (f2bf(v[1]) << 16),
                f2bf(v[2]) | (f2bf(v[3]) << 16) };
    if (g < M_) *(u32x2*)(xbf + (size_t)g * 64 + l * 2)        = p;
    else        *(u32x2*)(ebf + (size_t)(g - M_) * 64 + l * 2) = p;

    float ss = v[0]*v[0] + v[1]*v[1] + v[2]*v[2] + v[3]*v[3];
    ss += __shfl_xor(ss, 1);  ss += __shfl_xor(ss, 2);  ss += __shfl_xor(ss, 4);
    ss += __shfl_xor(ss, 8);  ss += __shfl_xor(ss, 16);
    if (l == 0) { if (g < M_) xsq[g] = ss; else esq[g - M_] = ss; }

    if (threadIdx.x < 8) {
        int idx = blockIdx.x * 8 + (int)threadIdx.x;
        if (idx < VP_) biasp[idx] = (idx < V_) ? bias[idx] : 0.f;
    }
}

// ---- GEMM 64x64, XCD-owned contiguous n-chunks, n-innermost per m-band ----
__global__ __launch_bounds__(256, 4)
void gemm_kernel(const unsigned int* __restrict__ xbf,
                 const unsigned int* __restrict__ ebf,
                 const float* __restrict__ xsq,
                 const float* __restrict__ esq,
                 const float* __restrict__ biasp,
                 float* __restrict__ out)
{
    // HW round-robins linear block id over 8 XCDs (grid is 1-D multiple of 8)
    const int bid = blockIdx.x;
    const int xcd = bid & 7;
    const int j   = bid >> 3;          // per-XCD sequential index, 0..1279
    const int dn  = j % 40;            // n-innermost within the XCD's chunk
    const int nt  = xcd * 40 + dn;
    if (nt >= NT_) return;             // padded tail (XCD 7), uniform exit
    const int mt  = ((j / 40) + 4 * xcd) & 31;   // stagger m-bands across XCDs
    const int m0  = mt * 64;
    const int n0  = nt * 64;

    __shared__ __align__(16) unsigned char smem[32 * 1024];
    unsigned char* a_t   = smem;               // 16 KB A tile (bf16, swizzled)
    unsigned char* b_t   = smem + 16 * 1024;   // 16 KB B tile
    unsigned char* otile = smem;               // aliased 16 KB f32 out tile

    const int tid  = threadIdx.x;
    const int lane = tid & 63;

    // stage A,B: swizzle via pre-swizzled SOURCE, linear LDS dest (validated r2)
    const char* asrc = (const char*)xbf + (size_t)m0 * 256;
    const char* bsrc = (const char*)ebf + (size_t)n0 * 256;   // n0+63 < VP, no guard
    #pragma unroll
    for (int i = 0; i < 4; ++i) {
        int c      = tid + i * 256;
        int row    = c >> 4;
        int within = (c & 15) * 16;
        int so     = row * 256 + (within ^ ((row & 7) << 4));
        unsigned ldsoff = (unsigned)(((tid & ~63) + i * 256) * 16);
        __builtin_amdgcn_global_load_lds(
            (const __attribute__((address_space(1))) unsigned int*)(asrc + so),
            (__attribute__((address_space(3))) unsigned int*)(a_t + ldsoff), 16, 0, 0);
        __builtin_amdgcn_global_load_lds(
            (const __attribute__((address_space(1))) unsigned int*)(bsrc + so),
            (__attribute__((address_space(3))) unsigned int*)(b_t + ldsoff), 16, 0, 0);
    }

    const int w  = tid >> 6;
    const int wm = w >> 1;
    const int wn = w & 1;
    const int lr = lane & 15;
    const int lk = lane >> 4;

    // hoisted epilogue operands (L2-hot ws; overlap with staging latency)
    const int   mloc0 = wm * 32 + lr;
    const int   mloc1 = mloc0 + 16;
    const float xs0   = xsq[m0 + mloc0];
    const float xs1   = xsq[m0 + mloc1];
    const int   nq0   = wn * 32 + lk * 4;
    const int   nq1   = nq0 + 16;
    const f32x4 es0   = *(const f32x4*)(esq   + n0 + nq0);
    const f32x4 es1   = *(const f32x4*)(esq   + n0 + nq1);
    const f32x4 bv0   = *(const f32x4*)(biasp + n0 + nq0);
    const f32x4 bv1   = *(const f32x4*)(biasp + n0 + nq1);

    __syncthreads();

    f32x4 acc[2][2] = {};
    #pragma unroll
    for (int kk = 0; kk < 4; ++kk) {
        int kb = kk * 64 + lk * 16;
        s16x8 a[2], b[2];
        #pragma unroll
        for (int mi = 0; mi < 2; ++mi) {
            int row = wm * 32 + mi * 16 + lr;
            a[mi] = *(const s16x8*)(&a_t[row * 256 + (kb ^ ((row & 7) << 4))]);
        }
        #pragma unroll
        for (int ni = 0; ni < 2; ++ni) {
            int row = wn * 32 + ni * 16 + lr;
            b[ni] = *(const s16x8*)(&b_t[row * 256 + (kb ^ ((row & 7) << 4))]);
        }
        #pragma unroll
        for (int mi = 0; mi < 2; ++mi)
            #pragma unroll
            for (int ni = 0; ni < 2; ++ni)
                // swapped operands: lane holds 4 consecutive n per fragment
                acc[mi][ni] = __builtin_amdgcn_mfma_f32_16x16x32_bf16(
                                  b[ni], a[mi], acc[mi][ni], 0, 0, 0);
    }

    __syncthreads();   // all waves done reading a_t/b_t -> safe to alias otile

    // write FINAL f32 values into swizzled otile
    // mapping: m = lane&15 (per mi), n = lk*4 + j (swapped m89 mapping)
    #pragma unroll
    for (int mi = 0; mi < 2; ++mi) {
        const int   mloc = (mi == 0) ? mloc0 : mloc1;
        const float xs   = (mi == 0) ? xs0   : xs1;
        #pragma unroll
        for (int ni = 0; ni < 2; ++ni) {
            const f32x4 es = (ni == 0) ? es0 : es1;
            const f32x4 bv = (ni == 0) ? bv0 : bv1;
            const int   nl = (ni == 0) ? nq0 : nq1;
            f32x4 r;
            #pragma unroll
            for (int jj = 0; jj < 4; ++jj) {
                float d2 = xs + es[jj] - 2.0f * acc[mi][ni][jj];
                r[jj] = bv[jj] - __builtin_amdgcn_sqrtf(fmaxf(d2, 0.0f));
            }
            *(f32x4*)(&otile[(mloc * 256 + nl * 4) ^ ((mloc & 7) << 4)]) = r;
        }
    }

    __syncthreads();

    // read back row-contiguous: wave w -> rows 16w..16w+15; 4 rows per instr
    const int rb = w * 16;
    if (n0 + 63 < V_) {
        #pragma unroll
        for (int i = 0; i < 4; ++i) {
            int r = rb + i * 4 + lk;
            f32x4 v = *(const f32x4*)(&otile[(r * 256 + lr * 16) ^ ((r & 7) << 4)]);
            *(f32x4u*)(out + (size_t)(m0 + r) * V_ + n0 + lr * 4) = v;
        }
    } else {
        #pragma unroll
        for (int i = 0; i < 4; ++i) {
            int r  = rb + i * 4 + lk;
            int gn = n0 + lr * 4;
            f32x4 v = *(const f32x4*)(&otile[(r * 256 + lr * 16) ^ ((r & 7) << 4)]);
            #pragma unroll
            for (int jj = 0; jj < 4; ++jj)
                if (gn + jj < V_) out[(size_t)(m0 + r) * V_ + gn + jj] = v[jj];
        }
    }
}

// ---------------- fallback (round-1 single kernel) if ws too small ----------------
__global__ __launch_bounds__(256, 2)
void l2head_fallback(const float* __restrict__ x,
                     const float* __restrict__ emb,
                     const float* __restrict__ bias,
                     float* __restrict__ out)
{
    __shared__ unsigned char a_raw[64 * 256];
    __shared__ unsigned char b_raw[64 * 256];
    __shared__ float xsq[64];
    __shared__ float esq[64];
    __shared__ float bls[64];

    const int tid  = threadIdx.x;
    const int lane = tid & 63;
    const int m0   = blockIdx.x * 64;
    const int n0   = blockIdx.y * 64;

    if (tid < 64) {
        int gn = n0 + tid;
        bls[tid] = (gn < V_) ? bias[gn] : 0.0f;
    }
    {
        const f32x4* src = (const f32x4*)(x + (size_t)m0 * H_);
        #pragma unroll
        for (int i = 0; i < 8; ++i) {
            int f = tid + i * 256, row = f >> 5, c4 = f & 31;
            f32x4 v = src[f];
            u32x2 p = { f2bf(v[0]) | (f2bf(v[1]) << 16),
                        f2bf(v[2]) | (f2bf(v[3]) << 16) };
            int boff = (c4 * 8) ^ ((row & 7) << 4);
            *(u32x2*)(&a_raw[row * 256 + boff]) = p;
            float ss = v[0]*v[0] + v[1]*v[1] + v[2]*v[2] + v[3]*v[3];
            ss += __shfl_xor(ss, 1);  ss += __shfl_xor(ss, 2);
            ss += __shfl_xor(ss, 4);  ss += __shfl_xor(ss, 8);
            ss += __shfl_xor(ss, 16);
            if ((lane & 31) == 0) xsq[row] = ss;
        }
    }
    {
        #pragma unroll
        for (int i = 0; i < 8; ++i) {
            int f = tid + i * 256, row = f >> 5, c4 = f & 31;
            int gn = n0 + row;
            f32x4 v = { 0.f, 0.f, 0.f, 0.f };
            if (gn < V_) v = *(const f32x4*)(emb + (size_t)gn * H_ + c4 * 4);
            u32x2 p = { f2bf(v[0]) | (f2bf(v[1]) << 16),
                        f2bf(v[2]) | (f2bf(v[3]) << 16) };
            int boff = (c4 * 8) ^ ((row & 7) << 4);
            *(u32x2*)(&b_raw[row * 256 + boff]) = p;
            float ss = v[0]*v[0] + v[1]*v[1] + v[2]*v[2] + v[3]*v[3];
            ss += __shfl_xor(ss, 1);  ss += __shfl_xor(ss, 2);
            ss += __shfl_xor(ss, 4);  ss += __shfl_xor(ss, 8);
            ss += __shfl_xor(ss, 16);
            if ((lane & 31) == 0) esq[row] = ss;
        }
    }
    __syncthreads();

    const int w  = tid >> 6;
    const int wm = w >> 1;
    const int wn = w & 1;
    const int lr = lane & 15;
    const int lk = lane >> 4;

    f32x4 acc[2][2] = {};
    #pragma unroll
    for (int kk = 0; kk < 4; ++kk) {
        int kb = kk * 64 + lk * 16;
        s16x8 a[2], b[2];
        #pragma unroll
        for (int mi = 0; mi < 2; ++mi) {
            int row = wm * 32 + mi * 16 + lr;
            a[mi] = *(const s16x8*)(&a_raw[row * 256 + (kb ^ ((row & 7) << 4))]);
        }
        #pragma unroll
        for (int ni = 0; ni < 2; ++ni) {
            int row = wn * 32 + ni * 16 + lr;
            b[ni] = *(const s16x8*)(&b_raw[row * 256 + (kb ^ ((row & 7) << 4))]);
        }
        #pragma unroll
        for (int mi = 0; mi < 2; ++mi)
            #pragma unroll
            for (int ni = 0; ni < 2; ++ni)
                acc[mi][ni] = __builtin_amdgcn_mfma_f32_16x16x32_bf16(
                                  a[mi], b[ni], acc[mi][ni], 0, 0, 0);
    }

    #pragma unroll
    for (int mi = 0; mi < 2; ++mi) {
        int mbase = wm * 32 + mi * 16 + lk * 4;
        #pragma unroll
        for (int ni = 0; ni < 2; ++ni) {
            int nloc = wn * 32 + ni * 16 + lr;
            int gn   = n0 + nloc;
            if (gn < V_) {
                float es = esq[nloc];
                float bb = bls[nloc];
                #pragma unroll
                for (int j = 0; j < 4; ++j) {
                    int   mloc = mbase + j;
                    float d2   = xsq[mloc] + es - 2.0f * acc[mi][ni][j];
                    out[(size_t)(m0 + mloc) * V_ + gn] = bb - __builtin_sqrtf(fmaxf(d2, 0.0f));
                }
            }
        }
    }
}

extern "C" void kernel_launch(void* const* d_in, const int* in_sizes, int n_in,
                              void* d_out, int out_size, void* d_ws, size_t ws_size,
                              hipStream_t stream) {
    const float* x    = (const float*)d_in[0];
    const float* emb  = (const float*)d_in[1];
    const float* bias = (const float*)d_in[2];
    float* out        = (float*)d_out;

    if (ws_size >= WS_END) {
        unsigned char* ws = (unsigned char*)d_ws;
        unsigned int* xbf = (unsigned int*)(ws + WS_XBF);
        unsigned int* ebf = (unsigned int*)(ws + WS_EBF);
        float* xsq        = (float*)(ws + WS_XSQ);
        float* esq        = (float*)(ws + WS_ESQ);
        float* biasp      = (float*)(ws + WS_BIA);

        prep_kernel<<<(M_ + VP_) / 8, 256, 0, stream>>>(x, emb, bias, xbf, ebf, xsq, esq, biasp);
        gemm_kernel<<<dim3(NTP_ * 32), dim3(256), 0, stream>>>(xbf, ebf, xsq, esq, biasp, out);
    } else {
        dim3 grid(M_ / 64, (V_ + 63) / 64);
        l2head_fallback<<<grid, dim3(256), 0, stream>>>(x, emb, bias, out);
    }
}